// Round 11
// baseline (101.324 us; speedup 1.0000x reference)
//
#include <hip/hip_runtime.h>
#include <math.h>

#define B_   8
#define L_   4096
#define D_   768
#define NC_  4096
#define NCH_ 2048
#define M_   (B_*NC_)    // 32768 (b,c) pairs
#define MC_  (B_*NCH_)   // 16384 active compact rows
#define NKT_ 24          // K-tiles of 32 (K=768)
#define META_BLOCKS 128
#define WPREP_BLOCKS 144
#define FUSED_BLOCKS 512 // BM=32 x BN=768

typedef __attribute__((ext_vector_type(8))) short short8;
typedef __attribute__((ext_vector_type(4))) float f32x4;
typedef unsigned int u32;
typedef unsigned short u16;

__device__ __forceinline__ void gload16(const void* g, void* l) {
    __builtin_amdgcn_global_load_lds((const __attribute__((address_space(1))) u32*)g,
                                     (__attribute__((address_space(3))) u32*)l, 16, 0, 0);
}

__device__ __forceinline__ u16 f2bf(float f) {           // RNE bf16
    union { float f; u32 u; } v; v.f = f;
    u32 r = v.u + 0x7fffu + ((v.u >> 16) & 1u);
    return (u16)(r >> 16);
}

// tanh(x) = 1 - 2/(e^{2x}+1). Saturates to +-1.
__device__ __forceinline__ float tanh_fast(float x) {
    float e = __builtin_amdgcn_exp2f(x * 2.885390081777927f);
    return 1.f - 2.f * __builtin_amdgcn_rcpf(e + 1.f);
}

__device__ __forceinline__ int lower_bound(const int* __restrict__ a, int lo, int hi, int v) {
    while (lo < hi) {
        int mid = (lo + hi) >> 1;
        if (a[mid] < v) lo = mid + 1; else hi = mid;
    }
    return lo;
}

// -------- kernel 1: prep = meta+keep (+wprep role blocks) --------
// meta: one thread per (b,c), idx = c*8+b; e via neighbor shuffle.
__global__ void prep_kernel(const int* __restrict__ seg,
                            const int* __restrict__ padm,
                            const int* __restrict__ regm,
                            const int* __restrict__ spm,
                            const float* __restrict__ Wm,
                            u16* __restrict__ wt,
                            int* __restrict__ stA, int* __restrict__ cntA,
                            int* __restrict__ act,
                            float* __restrict__ out_mp, float* __restrict__ out_mr,
                            float* __restrict__ out_sp,
                            float2* __restrict__ partials) {
    __shared__ float shm[64 * 65 + 8];
    int blk = blockIdx.x;
    int t = threadIdx.x;
    if (blk >= META_BLOCKS) {                    // ---- wprep role ----
        int wb = blk - META_BLOCKS;
        int bk = wb % 12, bn = wb / 12;
        int k0 = bk * 64, n0 = bn * 64;
        int ln = t & 63, lw = t >> 6;
        #pragma unroll
        for (int p = 0; p < 16; ++p) {
            int kl = lw + p * 4;
            shm[kl * 65 + ln] = Wm[(size_t)(k0 + kl) * D_ + n0 + ln];  // coalesced over n
        }
        __syncthreads();
        #pragma unroll
        for (int p = 0; p < 16; ++p) {
            int nl = lw + p * 4;
            wt[(size_t)(n0 + nl) * D_ + k0 + ln] = f2bf(shm[ln * 65 + nl]);
        }
        return;
    }
    // ---- meta role ----
    int idx = blk * 256 + t;                     // [0, M_)
    int c = idx >> 3, b = idx & 7;
    const int* row = seg + b * L_;
    int s = lower_bound(row, 0, L_, c);
    int e = __shfl_down(s, 8);                   // lane+8 holds (c+1, b)
    if ((t & 63) >= 56) e = lower_bound(row, s, L_, c + 1);
    int cnt = e - s;
    int mp = 0, mr = 0;
    if (cnt > 0) { mp = padm[b * L_ + s]; mr = regm[b * L_ + s]; }
    int sp = (mp == 0) ? -1 : spm[b * L_ + s];
    int k = mp;                                  // keep = OR of mp over the 8 b's
    k |= __shfl_xor(k, 1);
    k |= __shfl_xor(k, 2);
    k |= __shfl_xor(k, 4);
    k = k ? 1 : 0;
    out_mp[b * NC_ + c] = (float)mp;             // mp*keep == mp
    out_mr[b * NC_ + c] = (float)(k ? mr : 0);
    out_sp[b * NC_ + c] = (float)(k ? sp : 0);
    if (c < NCH_) {
        int mc = b * NCH_ + c;
        stA[mc] = s;
        cntA[mc] = cnt;
        act[mc] = (k && cnt > 0) ? 1 : 0;
    }
    float numP = (float)(k ? mr : 0);
    float denP = (float)(cnt * mr);
    #pragma unroll
    for (int off = 32; off; off >>= 1) {
        numP += __shfl_down(numP, off);
        denP += __shfl_down(denP, off);
    }
    __syncthreads();
    if ((t & 63) == 0) { shm[(t >> 6) * 2] = numP; shm[(t >> 6) * 2 + 1] = denP; }
    __syncthreads();
    if (t == 0)
        partials[blk] = make_float2(shm[0] + shm[2] + shm[4] + shm[6],
                                    shm[1] + shm[3] + shm[5] + shm[7]);
}

// -------- kernel 2: fused mean-prologue + A-in-LDS GEMM + dead-zero --------
// Block = 32 rows x 768 cols. Phase 1: all 8 waves compute the 32 chunk means
// (wave w -> chunks 4w..4w+3, coalesced 1KB row reads), bf16 into A-LDS
// ([kt][row][64B], slot-XOR swizzle = same layout as B tiles). Phase 2:
// ring-2 B pipeline (stage-after-barrier, vmcnt(0)/tile), 12 MFMA/kt/wave,
// A read from LDS (no HBM A traffic). Phase 3: epilogue + 98.3KB dead-zero.
__global__ __launch_bounds__(512, 1) void fused32_kernel(
        const float* __restrict__ x,
        const int* __restrict__ stA, const int* __restrict__ cntA,
        const u16* __restrict__ wt,               // [768][768] transposed bf16
        const float* __restrict__ bias,
        const int* __restrict__ act,
        const float2* __restrict__ partials,
        float* __restrict__ out, float* __restrict__ rateOut) {
    __shared__ char sAlds[49152];                 // 24 kt x 32 rows x 64 B
    __shared__ char sB[2 * 49152];                // ring-2 B tiles
    __shared__ int sMeta[64];                     // st[32], cnt[32]
    __shared__ float rb[4];
    int bid = blockIdx.x;
    int t = threadIdx.x;
    if (bid >= FUSED_BLOCKS) {                    // ---- rate role ----
        float n = 0.f, d = 0.f;
        if (t < META_BLOCKS) { float2 p = partials[t]; n = p.x; d = p.y; }
        #pragma unroll
        for (int off = 32; off; off >>= 1) { n += __shfl_down(n, off); d += __shfl_down(d, off); }
        if (t < META_BLOCKS && (t & 63) == 0) { rb[(t >> 6) * 2] = n; rb[(t >> 6) * 2 + 1] = d; }
        __syncthreads();
        if (t == 0) rateOut[0] = (rb[0] + rb[2]) / (rb[1] + rb[3]);
        return;
    }
    int wg = bid;
    int m0 = wg << 5;                             // 32 rows, all same b
    int b = m0 >> 11;
    int lane = t & 63, w = t >> 6;

    if (t < 32) { sMeta[t] = stA[m0 + t]; sMeta[32 + t] = cntA[m0 + t]; }

    const char* bT = (const char*)wt;             // 768 rows x 1536 B
    // B staging src offsets (inverse-swizzled), i = t + j*512
    int srcB[6];
    #pragma unroll
    for (int j = 0; j < 6; ++j) {
        int i = t + j * 512;
        int r = i >> 2, s = i & 3;
        srcB[j] = r * 1536 + ((s ^ ((r ^ (r >> 2)) & 3)) << 4);
    }
    int dbB = w * 1024;

    __syncthreads();                              // sMeta visible

    // issue B tile 0 early (hides under mean phase)
    #pragma unroll
    for (int j = 0; j < 6; ++j)
        gload16(bT + srcB[j], sB + j * 8192 + dbB);

    // ---- phase 1: mean -> A-LDS (wave w handles chunks 4w..4w+3) ----
    const float* xb = x + (size_t)b * L_ * D_;
    #pragma unroll 1
    for (int i = 0; i < 4; ++i) {
        int rr = (w << 2) + i;
        int st = sMeta[rr], cnt = sMeta[32 + rr];
        float a0=0.f,a1=0.f,a2=0.f,a3=0.f,a4=0.f,a5=0.f,
              a6=0.f,a7=0.f,a8=0.f,a9=0.f,a10=0.f,a11=0.f;
        const float4* base = (const float4*)(xb + (size_t)st * D_) + lane;
        for (int tk = 0; tk < cnt; ++tk) {
            const float4* p = base + (size_t)tk * 192;
            float4 v0 = p[0], v1 = p[64], v2 = p[128];
            a0 += v0.x; a1 += v0.y; a2  += v0.z; a3  += v0.w;
            a4 += v1.x; a5 += v1.y; a6  += v1.z; a7  += v1.w;
            a8 += v2.x; a9 += v2.y; a10 += v2.z; a11 += v2.w;
        }
        float inv = (cnt > 0) ? 1.f / (float)cnt : 0.f;
        int sw = (rr ^ (rr >> 2)) & 3;
        int kt0 = lane >> 3;
        int bofs = rr * 64 + ((((lane & 7) >> 1) ^ sw) << 4) + (lane & 1) * 8;
        u32 lo, hi;
        lo = (u32)f2bf(a0*inv) | ((u32)f2bf(a1*inv) << 16);
        hi = (u32)f2bf(a2*inv) | ((u32)f2bf(a3*inv) << 16);
        *(uint2*)(sAlds + kt0 * 2048 + bofs) = make_uint2(lo, hi);
        lo = (u32)f2bf(a4*inv) | ((u32)f2bf(a5*inv) << 16);
        hi = (u32)f2bf(a6*inv) | ((u32)f2bf(a7*inv) << 16);
        *(uint2*)(sAlds + (8 + kt0) * 2048 + bofs) = make_uint2(lo, hi);
        lo = (u32)f2bf(a8*inv) | ((u32)f2bf(a9*inv) << 16);
        hi = (u32)f2bf(a10*inv) | ((u32)f2bf(a11*inv) << 16);
        *(uint2*)(sAlds + (16 + kt0) * 2048 + bofs) = make_uint2(lo, hi);
    }
    __syncthreads();                              // A-LDS complete (drains vm+lgkm)

    // ---- phase 2: GEMM over 24 K-tiles ----
    int aoff[2], boff[6];
    #pragma unroll
    for (int f = 0; f < 2; ++f) {
        int r = f * 16 + (lane & 15);
        aoff[f] = r * 64 + ((((lane >> 4)) ^ ((r ^ (r >> 2)) & 3)) << 4);
    }
    #pragma unroll
    for (int g = 0; g < 6; ++g) {
        int r = w * 96 + g * 16 + (lane & 15);
        boff[g] = r * 64 + ((((lane >> 4)) ^ ((r ^ (r >> 2)) & 3)) << 4);
    }

    f32x4 acc[2][6] = {};

    #pragma unroll 1
    for (int kt = 0; kt < NKT_; ++kt) {
        asm volatile("s_waitcnt vmcnt(0)" ::: "memory");   // tile kt landed
        __builtin_amdgcn_s_barrier();
        __builtin_amdgcn_sched_barrier(0);
        const char* curA = sAlds + kt * 2048;
        const char* curB = sB + (kt & 1) * 49152;
        if (kt + 1 < NKT_) {                      // stage kt+1: safe after barrier
            int kof = (kt + 1) << 6;
            char* d = sB + ((kt + 1) & 1) * 49152;
            #pragma unroll
            for (int j = 0; j < 6; ++j)
                gload16(bT + srcB[j] + kof, d + j * 8192 + dbB);
        }
        short8 afr[2], bfr[6];
        #pragma unroll
        for (int f = 0; f < 2; ++f) afr[f] = *(const short8*)(curA + aoff[f]);
        #pragma unroll
        for (int g = 0; g < 6; ++g) bfr[g] = *(const short8*)(curB + boff[g]);
        __builtin_amdgcn_s_setprio(1);
        #pragma unroll
        for (int f = 0; f < 2; ++f)
            #pragma unroll
            for (int g = 0; g < 6; ++g)
                acc[f][g] = __builtin_amdgcn_mfma_f32_16x16x32_bf16(
                    afr[f], bfr[g], acc[f][g], 0, 0, 0);
        __builtin_amdgcn_s_setprio(0);
        __builtin_amdgcn_sched_barrier(0);
    }

    // ---- phase 3: epilogue (C/D map col=lane&15, row=(lane>>4)*4+reg) ----
    int ncol[6]; float bs[6];
    #pragma unroll
    for (int g = 0; g < 6; ++g) {
        ncol[g] = w * 96 + g * 16 + (lane & 15);
        bs[g] = bias[ncol[g]];
    }
    #pragma unroll
    for (int f = 0; f < 2; ++f) {
        int rbase = m0 + f * 16 + ((lane >> 4) << 2);
        #pragma unroll
        for (int q = 0; q < 4; ++q) {
            int mc = rbase + q;
            int av = act[mc];
            int gr = mc + ((mc >> 11) << 11);      // b*4096 + c
            size_t orow = (size_t)gr * D_;
            #pragma unroll
            for (int g = 0; g < 6; ++g) {
                float v = av ? tanh_fast(acc[f][g][q] + bs[g]) : 0.f;
                out[orow + ncol[g]] = v;
            }
        }
    }

    // dead-region zero: block share = 98304 B (50.33 MB / 512 blocks)
    {
        int sp = wg >> 6;
        size_t zb = (size_t)(sp * 4096 + 2048) * 3072 + (size_t)(wg & 63) * 98304;
        float4* pz = (float4*)((char*)out + zb);
        float4 zz = make_float4(0.f, 0.f, 0.f, 0.f);
        #pragma unroll
        for (int i = 0; i < 12; ++i) pz[t + i * 512] = zz;
    }
}

extern "C" void kernel_launch(void* const* d_in, const int* in_sizes, int n_in,
                              void* d_out, int out_size, void* d_ws, size_t ws_size,
                              hipStream_t stream) {
    const float* x    = (const float*)d_in[0];
    const int*   seg  = (const int*)d_in[1];
    const int*   padm = (const int*)d_in[2];
    const int*   regm = (const int*)d_in[3];
    const int*   spm  = (const int*)d_in[4];
    const float* Wm   = (const float*)d_in[5];
    const float* bias = (const float*)d_in[6];
    float* out = (float*)d_out;

    char* ws = (char*)d_ws;
    float2* partials = (float2*)ws;               // [128]
    int* stA  = (int*)(ws + 1024);                // [MC_] (b*2048+c)
    int* cntA = stA + MC_;
    int* act  = cntA + MC_;                       // [MC_]
    u16* wt   = (u16*)(act + MC_);                // 768*768 u16, 16B-aligned

    float* out_mp = out + (size_t)M_ * D_;
    float* out_mr = out_mp + M_;
    float* out_sp = out_mr + M_;
    float* out_rate = out_sp + M_;

    prep_kernel<<<META_BLOCKS + WPREP_BLOCKS, 256, 0, stream>>>(
        seg, padm, regm, spm, Wm, wt, stA, cntA, act,
        out_mp, out_mr, out_sp, partials);
    fused32_kernel<<<FUSED_BLOCKS + 1, 512, 0, stream>>>(
        x, stA, cntA, wt, bias, act, partials, out, out_rate);
}

// Round 12
// 73.386 us; speedup vs baseline: 1.3807x; 1.3807x over previous
//
#include <hip/hip_runtime.h>
#include <math.h>

#define B_   8
#define L_   4096
#define D_   768
#define NC_  4096
#define NCH_ 2048
#define M_   (B_*NC_)    // 32768 (b,c) pairs
#define MC_  (B_*NCH_)   // 16384 active compact rows
#define NKT_ 24          // K-tiles of 32 (K=768)
#define META_BLOCKS 128  // 128*256 == M_
#define GEMM_BLOCKS 256  // 256 mtiles (BM=64) x 1 ntile (BN=768), 1/CU
// mean-launch role layout
#define MEAN_N  MC_
#define ZERO_N  512
#define RATE_BID (MEAN_N + ZERO_N)
#define WPREP0  (RATE_BID + 1)
#define GRID_MEAN (WPREP0 + 144)

typedef __attribute__((ext_vector_type(8))) short short8;
typedef __attribute__((ext_vector_type(4))) float f32x4;
typedef unsigned int u32;
typedef unsigned short u16;

__device__ __forceinline__ void gload16(const void* g, void* l) {
    __builtin_amdgcn_global_load_lds((const __attribute__((address_space(1))) u32*)g,
                                     (__attribute__((address_space(3))) u32*)l, 16, 0, 0);
}

__device__ __forceinline__ u16 f2bf(float f) {           // RNE bf16
    union { float f; u32 u; } v; v.f = f;
    u32 r = v.u + 0x7fffu + ((v.u >> 16) & 1u);
    return (u16)(r >> 16);
}

// tanh(x) = 1 - 2/(e^{2x}+1). Saturates to +-1.
__device__ __forceinline__ float tanh_fast(float x) {
    float e = __builtin_amdgcn_exp2f(x * 2.885390081777927f);
    return 1.f - 2.f * __builtin_amdgcn_rcpf(e + 1.f);
}

// A-plane (bf16 of mean) lives in d_out's dead rows (c>=2048), spans 0..3.
__device__ __forceinline__ size_t aplane_byte(int mc) {
    int span = mc >> 12;
    int rem  = mc & 4095;
    return (size_t)(span * 4096 + 2048) * 3072 + (size_t)rem * 1536;
}

__device__ __forceinline__ int lower_bound(const int* __restrict__ a, int lo, int hi, int v) {
    while (lo < hi) {
        int mid = (lo + hi) >> 1;
        if (a[mid] < v) lo = mid + 1; else hi = mid;
    }
    return lo;
}

// -------- kernel 1: prep = meta+keep only (128 blocks x 256) --------
// One thread per (b,c), idx = c*8+b; e via neighbor shuffle; keep via shfl OR.
__global__ void prep_kernel(const int* __restrict__ seg,
                            const int* __restrict__ padm,
                            const int* __restrict__ regm,
                            const int* __restrict__ spm,
                            int* __restrict__ stA, int* __restrict__ cntA,
                            int* __restrict__ act,
                            float* __restrict__ out_mp, float* __restrict__ out_mr,
                            float* __restrict__ out_sp,
                            float2* __restrict__ partials) {
    __shared__ float shm[8];
    int blk = blockIdx.x;
    int t = threadIdx.x;
    int idx = blk * 256 + t;                     // [0, M_)
    int c = idx >> 3, b = idx & 7;
    const int* row = seg + b * L_;
    int s = lower_bound(row, 0, L_, c);
    int e = __shfl_down(s, 8);                   // lane+8 holds (c+1, b)
    if ((t & 63) >= 56) e = lower_bound(row, s, L_, c + 1);
    int cnt = e - s;
    int mp = 0, mr = 0;
    if (cnt > 0) { mp = padm[b * L_ + s]; mr = regm[b * L_ + s]; }
    int sp = (mp == 0) ? -1 : spm[b * L_ + s];
    int k = mp;                                  // keep = OR of mp over the 8 b's
    k |= __shfl_xor(k, 1);
    k |= __shfl_xor(k, 2);
    k |= __shfl_xor(k, 4);
    k = k ? 1 : 0;
    out_mp[b * NC_ + c] = (float)mp;             // mp*keep == mp
    out_mr[b * NC_ + c] = (float)(k ? mr : 0);
    out_sp[b * NC_ + c] = (float)(k ? sp : 0);
    if (c < NCH_) {
        int mc = b * NCH_ + c;
        stA[mc] = s;
        cntA[mc] = cnt;
        act[mc] = (k && cnt > 0) ? 1 : 0;
    }
    float numP = (float)(k ? mr : 0);
    float denP = (float)(cnt * mr);
    #pragma unroll
    for (int off = 32; off; off >>= 1) {
        numP += __shfl_down(numP, off);
        denP += __shfl_down(denP, off);
    }
    __syncthreads();
    if ((t & 63) == 0) { shm[(t >> 6) * 2] = numP; shm[(t >> 6) * 2 + 1] = denP; }
    __syncthreads();
    if (t == 0)
        partials[blk] = make_float2(shm[0] + shm[2] + shm[4] + shm[6],
                                    shm[1] + shm[3] + shm[5] + shm[7]);
}

// -------- kernel 2: mean (+zero spans 4-7, +rate, +wprep roles) --------
// 192 threads. Roles: [0,16384) mean; [16384,16896) zero; 16896 rate;
// [16897,17041) wprep (hides under the mean stream).
__global__ void mean_kernel(const float* __restrict__ x,
                            const int* __restrict__ stA,
                            const int* __restrict__ cntA,
                            const float* __restrict__ Wm,
                            u16* __restrict__ wt,
                            char* __restrict__ outb,
                            const float2* __restrict__ partials,
                            float* __restrict__ rateOut) {
    __shared__ float shm[64 * 65];
    int mc = blockIdx.x;
    int t = threadIdx.x;                 // 0..191
    if (mc >= MEAN_N) {
        if (mc < RATE_BID) {             // ---- zero role: spans 4..7 (25.2 MB) ----
            int z = mc - MEAN_N;         // 0..511
            int sp = z >> 7;
            size_t base = (size_t)((4 + sp) * 4096 + 2048) * 3072 + (size_t)(z & 127) * 49152;
            float4* p = (float4*)(outb + base);
            float4 zz = make_float4(0.f, 0.f, 0.f, 0.f);
            #pragma unroll
            for (int i = 0; i < 16; ++i) p[t + i * 192] = zz;
            return;
        }
        if (mc == RATE_BID) {            // ---- rate role ----
            float n = 0.f, d = 0.f;
            if (t < META_BLOCKS) { float2 p = partials[t]; n = p.x; d = p.y; }
            #pragma unroll
            for (int off = 32; off; off >>= 1) { n += __shfl_down(n, off); d += __shfl_down(d, off); }
            if (t < META_BLOCKS && (t & 63) == 0) { shm[(t >> 6) * 2] = n; shm[(t >> 6) * 2 + 1] = d; }
            __syncthreads();
            if (t == 0) rateOut[0] = (shm[0] + shm[2]) / (shm[1] + shm[3]);
            return;
        }
        // ---- wprep role: W[k][n] -> wt[n][k] bf16 via LDS transpose ----
        int wb = mc - WPREP0;            // 0..143
        int bk = wb % 12, bn = wb / 12;
        int k0 = bk * 64, n0 = bn * 64;
        for (int i = t; i < 4096; i += 192) {
            int kl = i >> 6, ln = i & 63;
            shm[kl * 65 + ln] = Wm[(size_t)(k0 + kl) * D_ + n0 + ln];  // coalesced over n
        }
        __syncthreads();
        for (int i = t; i < 4096; i += 192) {
            int nl = i >> 6, ln = i & 63;
            wt[(size_t)(n0 + nl) * D_ + k0 + ln] = f2bf(shm[ln * 65 + nl]);
        }
        return;
    }
    // ---- mean role ----
    int b = mc >> 11, c = mc & (NCH_ - 1);
    int idx = b * NCH_ + c;
    int cnt = cntA[idx], s = stA[idx];
    float ax = 0.f, ay = 0.f, az = 0.f, aw = 0.f;
    if (cnt > 0) {
        const float4* base = (const float4*)(x + ((size_t)b * L_ + s) * D_) + t;
        int tk = 0;
        for (; tk + 2 <= cnt; tk += 2) {         // 2-token unroll: 2 loads in flight
            float4 v0 = base[tk * 192];
            float4 v1 = base[(tk + 1) * 192];
            ax += v0.x + v1.x; ay += v0.y + v1.y;
            az += v0.z + v1.z; aw += v0.w + v1.w;
        }
        if (tk < cnt) {
            float4 v0 = base[tk * 192];
            ax += v0.x; ay += v0.y; az += v0.z; aw += v0.w;
        }
        float inv = 1.f / (float)cnt;
        ax *= inv; ay *= inv; az *= inv; aw *= inv;
    }
    u16* hi = (u16*)(outb + aplane_byte(mc));
    ushort4 h;
    h.x = f2bf(ax); h.y = f2bf(ay); h.z = f2bf(az); h.w = f2bf(aw);
    *(ushort4*)(hi + 4 * t) = h;
}

// -------- kernel 3: 64x768 deep-pipelined MFMA GEMM + early self-zero ----
// Block = sole reader of its 96KB A region. Ring-3 (A 3x4KB + B 3x48KB),
// staging 2 K-tiles ahead, 7 gloads/wave/K-tile, counted vmcnt(7), one
// s_barrier per K-tile, 2 phases x 12 MFMA + setprio. Self-zero stores are
// issued right after the final vmcnt(0) drain so they overlap the epilogue.
__global__ __launch_bounds__(512, 1) void gemm8_kernel(
        const char* __restrict__ aBytes,          // d_out bytes (A plane)
        const u16* __restrict__ wt,               // [768][768] transposed bf16
        const float* __restrict__ bias,
        const int* __restrict__ act,
        float* __restrict__ out) {
    __shared__ char sAB[159744];                  // A ring 0..12287, B ring 12288..
    char* sA = sAB;
    char* sB = sAB + 12288;
    int bid = blockIdx.x;
    int t = threadIdx.x;
    int wg = (bid & 7) * 32 + (bid >> 3);         // XCD-chunked (256 = 8*32)
    int m0 = wg << 6;
    int lane = t & 63, w = t >> 6;

    const char* aT = aBytes + aplane_byte(m0);    // 64 rows x 1536 B
    const char* bT = (const char*)wt;             // 768 rows x 1536 B

    // A staging src (wave halves duplicate: ta in [0,256))
    int ta = t & 255;
    int rA = ta >> 2, sa = ta & 3;
    int srcA = rA * 1536 + ((sa ^ ((rA ^ (rA >> 2)) & 3)) << 4);
    int dbA = (w & 3) * 1024;
    // B staging src: call j covers rows via i = t + j*512
    int srcB[6];
    #pragma unroll
    for (int j = 0; j < 6; ++j) {
        int i = t + j * 512;
        int r = i >> 2, s = i & 3;
        srcB[j] = r * 1536 + ((s ^ ((r ^ (r >> 2)) & 3)) << 4);
    }
    int dbB = w * 1024;

    // fragment read offsets (swizzled, loop-invariant)
    int aoff[4], boff[6];
    #pragma unroll
    for (int f = 0; f < 4; ++f) {
        int r = f * 16 + (lane & 15);
        aoff[f] = r * 64 + ((((lane >> 4)) ^ ((r ^ (r >> 2)) & 3)) << 4);
    }
    #pragma unroll
    for (int g = 0; g < 6; ++g) {
        int r = w * 96 + g * 16 + (lane & 15);
        boff[g] = r * 64 + ((((lane >> 4)) ^ ((r ^ (r >> 2)) & 3)) << 4);
    }

    f32x4 acc[4][6] = {};

    // prologue: stage K-tiles 0,1 (order per tile: A, B0..B5)
    #pragma unroll
    for (int p = 0; p < 2; ++p) {
        int kof = p << 6;
        gload16(aT + srcA + kof, sA + p * 4096 + dbA);
        #pragma unroll
        for (int j = 0; j < 6; ++j)
            gload16(bT + srcB[j] + kof, sB + p * 49152 + j * 8192 + dbB);
    }

    int cur = 0;
    #pragma unroll 1
    for (int kt = 0; kt < NKT_; ++kt) {
        // tile kt's 7 loads oldest; <=7 newer (tile kt+1) stay in flight
        if (kt < NKT_ - 1) asm volatile("s_waitcnt vmcnt(7)" ::: "memory");
        else               asm volatile("s_waitcnt vmcnt(0)" ::: "memory");
        __builtin_amdgcn_s_barrier();
        __builtin_amdgcn_sched_barrier(0);
        if (kt == NKT_ - 1) {
            // early self-zero: all A gloads drained; stores overlap last tile's
            // MFMA + epilogue. This block is the sole reader of its A region.
            float4* pz = (float4*)((char*)out + aplane_byte(m0));
            float4 zz = make_float4(0.f, 0.f, 0.f, 0.f);
            #pragma unroll
            for (int i = 0; i < 12; ++i) pz[t + i * 512] = zz;
        }
        const char* curA = sA + cur * 4096;
        const char* curB = sB + cur * 49152;
        int nxt = cur + 2; if (nxt >= 3) nxt -= 3;
        int kof = (kt + 2) << 6;
        bool st = (kt + 2 < NKT_);
        // ---- phase A: A-frags + B-frags g0-2; stage A,B0,B1,B2; 12 MFMA ----
        short8 afr[4], bfr[3];
        #pragma unroll
        for (int f = 0; f < 4; ++f) afr[f] = *(const short8*)(curA + aoff[f]);
        #pragma unroll
        for (int g = 0; g < 3; ++g) bfr[g] = *(const short8*)(curB + boff[g]);
        if (st) {
            gload16(aT + srcA + kof, sA + nxt * 4096 + dbA);
            gload16(bT + srcB[0] + kof, sB + nxt * 49152 + dbB);
            gload16(bT + srcB[1] + kof, sB + nxt * 49152 + 8192 + dbB);
            gload16(bT + srcB[2] + kof, sB + nxt * 49152 + 16384 + dbB);
        }
        __builtin_amdgcn_s_setprio(1);
        #pragma unroll
        for (int f = 0; f < 4; ++f)
            #pragma unroll
            for (int g = 0; g < 3; ++g)
                acc[f][g] = __builtin_amdgcn_mfma_f32_16x16x32_bf16(
                    afr[f], bfr[g], acc[f][g], 0, 0, 0);
        __builtin_amdgcn_s_setprio(0);
        // ---- phase B: B-frags g3-5; stage B3,B4,B5; 12 MFMA ----
        short8 bfr2[3];
        #pragma unroll
        for (int g = 0; g < 3; ++g) bfr2[g] = *(const short8*)(curB + boff[g + 3]);
        if (st) {
            gload16(bT + srcB[3] + kof, sB + nxt * 49152 + 24576 + dbB);
            gload16(bT + srcB[4] + kof, sB + nxt * 49152 + 32768 + dbB);
            gload16(bT + srcB[5] + kof, sB + nxt * 49152 + 40960 + dbB);
        }
        __builtin_amdgcn_s_setprio(1);
        #pragma unroll
        for (int f = 0; f < 4; ++f)
            #pragma unroll
            for (int g = 0; g < 3; ++g)
                acc[f][g + 3] = __builtin_amdgcn_mfma_f32_16x16x32_bf16(
                    afr[f], bfr2[g], acc[f][g + 3], 0, 0, 0);
        __builtin_amdgcn_s_setprio(0);
        __builtin_amdgcn_sched_barrier(0);
        if (++cur == 3) cur = 0;
    }

    // epilogue: C/D lane map col=lane&15, row=(lane>>4)*4+reg
    int ncol[6]; float bs[6];
    #pragma unroll
    for (int g = 0; g < 6; ++g) {
        ncol[g] = w * 96 + g * 16 + (lane & 15);
        bs[g] = bias[ncol[g]];
    }
    #pragma unroll
    for (int f = 0; f < 4; ++f) {
        int rbase = m0 + f * 16 + ((lane >> 4) << 2);
        #pragma unroll
        for (int q = 0; q < 4; ++q) {
            int mc = rbase + q;
            int av = act[mc];
            int gr = mc + ((mc >> 11) << 11);      // b*4096 + c
            size_t orow = (size_t)gr * D_;
            #pragma unroll
            for (int g = 0; g < 6; ++g) {
                float v = av ? tanh_fast(acc[f][g][q] + bs[g]) : 0.f;
                out[orow + ncol[g]] = v;
            }
        }
    }
}

extern "C" void kernel_launch(void* const* d_in, const int* in_sizes, int n_in,
                              void* d_out, int out_size, void* d_ws, size_t ws_size,
                              hipStream_t stream) {
    const float* x    = (const float*)d_in[0];
    const int*   seg  = (const int*)d_in[1];
    const int*   padm = (const int*)d_in[2];
    const int*   regm = (const int*)d_in[3];
    const int*   spm  = (const int*)d_in[4];
    const float* Wm   = (const float*)d_in[5];
    const float* bias = (const float*)d_in[6];
    float* out = (float*)d_out;

    char* ws = (char*)d_ws;
    float2* partials = (float2*)ws;               // [128]
    int* stA  = (int*)(ws + 1024);                // [MC_] (b*2048+c)
    int* cntA = stA + MC_;
    int* act  = cntA + MC_;                       // [MC_]
    u16* wt   = (u16*)(act + MC_);                // 768*768 u16, 16B-aligned

    float* out_mp = out + (size_t)M_ * D_;
    float* out_mr = out_mp + M_;
    float* out_sp = out_mr + M_;
    float* out_rate = out_sp + M_;

    prep_kernel<<<META_BLOCKS, 256, 0, stream>>>(
        seg, padm, regm, spm, stA, cntA, act, out_mp, out_mr, out_sp, partials);
    mean_kernel<<<GRID_MEAN, 192, 0, stream>>>(
        x, stA, cntA, Wm, wt, (char*)d_out, partials, out_rate);
    gemm8_kernel<<<GEMM_BLOCKS, 512, 0, stream>>>(
        (const char*)d_out, wt, bias, act, out);
}

// Round 13
// 72.337 us; speedup vs baseline: 1.4007x; 1.0145x over previous
//
#include <hip/hip_runtime.h>
#include <math.h>

#define B_   8
#define L_   4096
#define D_   768
#define NC_  4096
#define NCH_ 2048
#define M_   (B_*NC_)    // 32768 (b,c) pairs
#define MC_  (B_*NCH_)   // 16384 active compact rows
#define NKT_ 24          // K-tiles of 32 (K=768)
#define META_BLOCKS 128
#define WPREP_BLOCKS 144
#define GEMM_BLOCKS 256  // 256 mtiles (BM=64) x 1 ntile (BN=768), 1/CU
#define MEAN_ZB 512      // zero-role blocks in mean grid (spans 4..7)

typedef __attribute__((ext_vector_type(8))) short short8;
typedef __attribute__((ext_vector_type(4))) float f32x4;
typedef unsigned int u32;
typedef unsigned short u16;

__device__ __forceinline__ void gload16(const void* g, void* l) {
    __builtin_amdgcn_global_load_lds((const __attribute__((address_space(1))) u32*)g,
                                     (__attribute__((address_space(3))) u32*)l, 16, 0, 0);
}

__device__ __forceinline__ u16 f2bf(float f) {           // RNE bf16
    union { float f; u32 u; } v; v.f = f;
    u32 r = v.u + 0x7fffu + ((v.u >> 16) & 1u);
    return (u16)(r >> 16);
}

// tanh(x) = 1 - 2/(e^{2x}+1). Saturates to +-1.
__device__ __forceinline__ float tanh_fast(float x) {
    float e = __builtin_amdgcn_exp2f(x * 2.885390081777927f);
    return 1.f - 2.f * __builtin_amdgcn_rcpf(e + 1.f);
}

// A-plane (bf16 of mean) lives in d_out's dead rows (c>=2048), spans 0..3.
__device__ __forceinline__ size_t aplane_byte(int mc) {
    int span = mc >> 12;
    int rem  = mc & 4095;
    return (size_t)(span * 4096 + 2048) * 3072 + (size_t)rem * 1536;
}

__device__ __forceinline__ int lower_bound(const int* __restrict__ a, int lo, int hi, int v) {
    while (lo < hi) {
        int mid = (lo + hi) >> 1;
        if (a[mid] < v) lo = mid + 1; else hi = mid;
    }
    return lo;
}

// -------- kernel 1: prep = meta+keep (+wprep role blocks) --------
__global__ void prep_kernel(const int* __restrict__ seg,
                            const int* __restrict__ padm,
                            const int* __restrict__ regm,
                            const int* __restrict__ spm,
                            const float* __restrict__ Wm,
                            u16* __restrict__ wt,
                            int* __restrict__ stA, int* __restrict__ cntA,
                            int* __restrict__ act,
                            float* __restrict__ out_mp, float* __restrict__ out_mr,
                            float* __restrict__ out_sp,
                            float2* __restrict__ partials) {
    __shared__ float shm[64 * 65 + 8];
    int blk = blockIdx.x;
    int t = threadIdx.x;
    if (blk >= META_BLOCKS) {                    // ---- wprep role ----
        int wb = blk - META_BLOCKS;
        int bk = wb % 12, bn = wb / 12;
        int k0 = bk * 64, n0 = bn * 64;
        int ln = t & 63, lw = t >> 6;
        #pragma unroll
        for (int p = 0; p < 16; ++p) {
            int kl = lw + p * 4;
            shm[kl * 65 + ln] = Wm[(size_t)(k0 + kl) * D_ + n0 + ln];  // coalesced over n
        }
        __syncthreads();
        #pragma unroll
        for (int p = 0; p < 16; ++p) {
            int nl = lw + p * 4;
            wt[(size_t)(n0 + nl) * D_ + k0 + ln] = f2bf(shm[ln * 65 + nl]);
        }
        return;
    }
    // ---- meta role ----
    int idx = blk * 256 + t;                     // [0, M_)
    int c = idx >> 3, b = idx & 7;
    const int* row = seg + b * L_;
    int s = lower_bound(row, 0, L_, c);
    int e = __shfl_down(s, 8);                   // lane+8 holds (c+1, b)
    if ((t & 63) >= 56) e = lower_bound(row, s, L_, c + 1);
    int cnt = e - s;
    int mp = 0, mr = 0;
    if (cnt > 0) { mp = padm[b * L_ + s]; mr = regm[b * L_ + s]; }
    int sp = (mp == 0) ? -1 : spm[b * L_ + s];
    int k = mp;                                  // keep = OR of mp over the 8 b's
    k |= __shfl_xor(k, 1);
    k |= __shfl_xor(k, 2);
    k |= __shfl_xor(k, 4);
    k = k ? 1 : 0;
    out_mp[b * NC_ + c] = (float)mp;             // mp*keep == mp
    out_mr[b * NC_ + c] = (float)(k ? mr : 0);
    out_sp[b * NC_ + c] = (float)(k ? sp : 0);
    if (c < NCH_) {
        int mc = b * NCH_ + c;
        stA[mc] = s;
        cntA[mc] = cnt;
        act[mc] = (k && cnt > 0) ? 1 : 0;
    }
    float numP = (float)(k ? mr : 0);
    float denP = (float)(cnt * mr);
    #pragma unroll
    for (int off = 32; off; off >>= 1) {
        numP += __shfl_down(numP, off);
        denP += __shfl_down(denP, off);
    }
    __syncthreads();
    if ((t & 63) == 0) { shm[(t >> 6) * 2] = numP; shm[(t >> 6) * 2 + 1] = denP; }
    __syncthreads();
    if (t == 0)
        partials[blk] = make_float2(shm[0] + shm[2] + shm[4] + shm[6],
                                    shm[1] + shm[3] + shm[5] + shm[7]);
}

// -------- kernel 2: mean -> bf16 A-plane; + zero spans 4-7; + rate --------
__global__ void mean_kernel(const float* __restrict__ x,
                            const int* __restrict__ stA,
                            const int* __restrict__ cntA,
                            char* __restrict__ outb,
                            const float2* __restrict__ partials,
                            float* __restrict__ rateOut) {
    __shared__ float rbuf[4];
    int mc = blockIdx.x;
    int t = threadIdx.x;                 // 0..191
    if (mc == MC_ + MEAN_ZB) {           // ---- rate role (1 block) ----
        float n = 0.f, d = 0.f;
        if (t < META_BLOCKS) { float2 p = partials[t]; n = p.x; d = p.y; }
        #pragma unroll
        for (int off = 32; off; off >>= 1) { n += __shfl_down(n, off); d += __shfl_down(d, off); }
        if (t < META_BLOCKS && (t & 63) == 0) { rbuf[(t >> 6) * 2] = n; rbuf[(t >> 6) * 2 + 1] = d; }
        __syncthreads();
        if (t == 0) rateOut[0] = (rbuf[0] + rbuf[2]) / (rbuf[1] + rbuf[3]);
        return;
    }
    if (mc >= MC_) {                     // ---- zero role: spans 4..7 (25.2 MB) ----
        int z = mc - MC_;                // 0..511
        int sp = z >> 7;
        size_t base = (size_t)((4 + sp) * 4096 + 2048) * 3072 + (size_t)(z & 127) * 49152;
        float4* p = (float4*)(outb + base);
        float4 zz = make_float4(0.f, 0.f, 0.f, 0.f);
        #pragma unroll
        for (int i = 0; i < 16; ++i) p[t + i * 192] = zz;
        return;
    }
    // ---- mean role ----
    int b = mc >> 11, c = mc & (NCH_ - 1);
    int idx = b * NCH_ + c;
    int cnt = cntA[idx], s = stA[idx];
    float ax = 0.f, ay = 0.f, az = 0.f, aw = 0.f;
    if (cnt > 0) {
        const float4* base = (const float4*)(x + ((size_t)b * L_ + s) * D_) + t;
        int tk = 0;
        for (; tk + 2 <= cnt; tk += 2) {         // 2-token unroll: 2 loads in flight
            float4 v0 = base[tk * 192];
            float4 v1 = base[(tk + 1) * 192];
            ax += v0.x + v1.x; ay += v0.y + v1.y;
            az += v0.z + v1.z; aw += v0.w + v1.w;
        }
        if (tk < cnt) {
            float4 v0 = base[tk * 192];
            ax += v0.x; ay += v0.y; az += v0.z; aw += v0.w;
        }
        float inv = 1.f / (float)cnt;
        ax *= inv; ay *= inv; az *= inv; aw *= inv;
    }
    u16* hi = (u16*)(outb + aplane_byte(mc));
    ushort4 h;
    h.x = f2bf(ax); h.y = f2bf(ay); h.z = f2bf(az); h.w = f2bf(aw);
    *(ushort4*)(hi + 4 * t) = h;
}

// -------- kernel 3: 64x768 deep-pipelined MFMA GEMM + self-zeroing --------
// Block = sole reader of its 96KB A region -> zeroes it in the epilogue.
// Ring-3 (A 3x4KB + B 3x48KB = 156KB LDS), staging 2 K-tiles ahead,
// 7 gloads/wave/K-tile (A duplicated across wave halves), counted vmcnt(7),
// one s_barrier per K-tile, 2 phases x 12 MFMA + setprio.
__global__ __launch_bounds__(512, 1) void gemm8_kernel(
        const char* __restrict__ aBytes,          // d_out bytes (A plane)
        const u16* __restrict__ wt,               // [768][768] transposed bf16
        const float* __restrict__ bias,
        const int* __restrict__ act,
        float* __restrict__ out) {
    __shared__ char sAB[159744];                  // A ring 0..12287, B ring 12288..
    char* sA = sAB;
    char* sB = sAB + 12288;
    int bid = blockIdx.x;
    int t = threadIdx.x;
    int wg = (bid & 7) * 32 + (bid >> 3);         // XCD-chunked (256 = 8*32)
    int m0 = wg << 6;
    int lane = t & 63, w = t >> 6;

    const char* aT = aBytes + aplane_byte(m0);    // 64 rows x 1536 B
    const char* bT = (const char*)wt;             // 768 rows x 1536 B

    // A staging src (wave halves duplicate: ta in [0,256))
    int ta = t & 255;
    int rA = ta >> 2, sa = ta & 3;
    int srcA = rA * 1536 + ((sa ^ ((rA ^ (rA >> 2)) & 3)) << 4);
    int dbA = (w & 3) * 1024;
    // B staging src: call j covers rows via i = t + j*512
    int srcB[6];
    #pragma unroll
    for (int j = 0; j < 6; ++j) {
        int i = t + j * 512;
        int r = i >> 2, s = i & 3;
        srcB[j] = r * 1536 + ((s ^ ((r ^ (r >> 2)) & 3)) << 4);
    }
    int dbB = w * 1024;

    // fragment read offsets (swizzled, loop-invariant)
    int aoff[4], boff[6];
    #pragma unroll
    for (int f = 0; f < 4; ++f) {
        int r = f * 16 + (lane & 15);
        aoff[f] = r * 64 + ((((lane >> 4)) ^ ((r ^ (r >> 2)) & 3)) << 4);
    }
    #pragma unroll
    for (int g = 0; g < 6; ++g) {
        int r = w * 96 + g * 16 + (lane & 15);
        boff[g] = r * 64 + ((((lane >> 4)) ^ ((r ^ (r >> 2)) & 3)) << 4);
    }

    f32x4 acc[4][6] = {};

    // prologue: stage K-tiles 0,1 (order per tile: A, B0..B5)
    #pragma unroll
    for (int p = 0; p < 2; ++p) {
        int kof = p << 6;
        gload16(aT + srcA + kof, sA + p * 4096 + dbA);
        #pragma unroll
        for (int j = 0; j < 6; ++j)
            gload16(bT + srcB[j] + kof, sB + p * 49152 + j * 8192 + dbB);
    }

    int cur = 0;
    #pragma unroll 1
    for (int kt = 0; kt < NKT_; ++kt) {
        // tile kt's 7 loads oldest; <=7 newer (tile kt+1) stay in flight
        if (kt < NKT_ - 1) asm volatile("s_waitcnt vmcnt(7)" ::: "memory");
        else               asm volatile("s_waitcnt vmcnt(0)" ::: "memory");
        __builtin_amdgcn_s_barrier();
        __builtin_amdgcn_sched_barrier(0);
        const char* curA = sA + cur * 4096;
        const char* curB = sB + cur * 49152;
        int nxt = cur + 2; if (nxt >= 3) nxt -= 3;
        int kof = (kt + 2) << 6;
        bool st = (kt + 2 < NKT_);
        // ---- phase A: A-frags + B-frags g0-2; stage A,B0,B1,B2; 12 MFMA ----
        short8 afr[4], bfr[3];
        #pragma unroll
        for (int f = 0; f < 4; ++f) afr[f] = *(const short8*)(curA + aoff[f]);
        #pragma unroll
        for (int g = 0; g < 3; ++g) bfr[g] = *(const short8*)(curB + boff[g]);
        if (st) {
            gload16(aT + srcA + kof, sA + nxt * 4096 + dbA);
            gload16(bT + srcB[0] + kof, sB + nxt * 49152 + dbB);
            gload16(bT + srcB[1] + kof, sB + nxt * 49152 + 8192 + dbB);
            gload16(bT + srcB[2] + kof, sB + nxt * 49152 + 16384 + dbB);
        }
        __builtin_amdgcn_s_setprio(1);
        #pragma unroll
        for (int f = 0; f < 4; ++f)
            #pragma unroll
            for (int g = 0; g < 3; ++g)
                acc[f][g] = __builtin_amdgcn_mfma_f32_16x16x32_bf16(
                    afr[f], bfr[g], acc[f][g], 0, 0, 0);
        __builtin_amdgcn_s_setprio(0);
        // ---- phase B: B-frags g3-5; stage B3,B4,B5; 12 MFMA ----
        short8 bfr2[3];
        #pragma unroll
        for (int g = 0; g < 3; ++g) bfr2[g] = *(const short8*)(curB + boff[g + 3]);
        if (st) {
            gload16(bT + srcB[3] + kof, sB + nxt * 49152 + 24576 + dbB);
            gload16(bT + srcB[4] + kof, sB + nxt * 49152 + 32768 + dbB);
            gload16(bT + srcB[5] + kof, sB + nxt * 49152 + 40960 + dbB);
        }
        __builtin_amdgcn_s_setprio(1);
        #pragma unroll
        for (int f = 0; f < 4; ++f)
            #pragma unroll
            for (int g = 0; g < 3; ++g)
                acc[f][g + 3] = __builtin_amdgcn_mfma_f32_16x16x32_bf16(
                    afr[f], bfr2[g], acc[f][g + 3], 0, 0, 0);
        __builtin_amdgcn_s_setprio(0);
        __builtin_amdgcn_sched_barrier(0);
        if (++cur == 3) cur = 0;
    }

    // epilogue: C/D lane map col=lane&15, row=(lane>>4)*4+reg
    int ncol[6]; float bs[6];
    #pragma unroll
    for (int g = 0; g < 6; ++g) {
        ncol[g] = w * 96 + g * 16 + (lane & 15);
        bs[g] = bias[ncol[g]];
    }
    #pragma unroll
    for (int f = 0; f < 4; ++f) {
        int rbase = m0 + f * 16 + ((lane >> 4) << 2);
        #pragma unroll
        for (int q = 0; q < 4; ++q) {
            int mc = rbase + q;
            int av = act[mc];
            int gr = mc + ((mc >> 11) << 11);      // b*4096 + c
            size_t orow = (size_t)gr * D_;
            #pragma unroll
            for (int g = 0; g < 6; ++g) {
                float v = av ? tanh_fast(acc[f][g][q] + bs[g]) : 0.f;
                out[orow + ncol[g]] = v;
            }
        }
    }

    // self-zero: this block is the sole reader of its A region (96 KB)
    float4* pz = (float4*)((char*)out + aplane_byte(m0));
    float4 zz = make_float4(0.f, 0.f, 0.f, 0.f);
    #pragma unroll
    for (int i = 0; i < 12; ++i) pz[t + i * 512] = zz;
}

extern "C" void kernel_launch(void* const* d_in, const int* in_sizes, int n_in,
                              void* d_out, int out_size, void* d_ws, size_t ws_size,
                              hipStream_t stream) {
    const float* x    = (const float*)d_in[0];
    const int*   seg  = (const int*)d_in[1];
    const int*   padm = (const int*)d_in[2];
    const int*   regm = (const int*)d_in[3];
    const int*   spm  = (const int*)d_in[4];
    const float* Wm   = (const float*)d_in[5];
    const float* bias = (const float*)d_in[6];
    float* out = (float*)d_out;

    char* ws = (char*)d_ws;
    float2* partials = (float2*)ws;               // [128]
    int* stA  = (int*)(ws + 1024);                // [MC_] (b*2048+c)
    int* cntA = stA + MC_;
    int* act  = cntA + MC_;                       // [MC_]
    u16* wt   = (u16*)(act + MC_);                // 768*768 u16, 16B-aligned

    float* out_mp = out + (size_t)M_ * D_;
    float* out_mr = out_mp + M_;
    float* out_sp = out_mr + M_;
    float* out_rate = out_sp + M_;

    prep_kernel<<<META_BLOCKS + WPREP_BLOCKS, 256, 0, stream>>>(
        seg, padm, regm, spm, Wm, wt, stA, cntA, act,
        out_mp, out_mr, out_sp, partials);
    mean_kernel<<<MC_ + MEAN_ZB + 1, 192, 0, stream>>>(
        x, stA, cntA, (char*)d_out, partials, out_rate);
    gemm8_kernel<<<GEMM_BLOCKS, 512, 0, stream>>>(
        (const char*)d_out, wt, bias, act, out);
}